// Round 1
// baseline (460.953 us; speedup 1.0000x reference)
//
#include <hip/hip_runtime.h>

// Fused ShiftedWindowMSA: x->qkv (GEMM1) -> windowed attention -> proj (GEMM2)
// One workgroup per (batch, window): grid 64*64=4096, 256 threads (4 waves).
// f16 MFMA 16x16x32 throughout, fp32 accumulation.

typedef _Float16 f16;
typedef _Float16 f16x4 __attribute__((ext_vector_type(4)));
typedef _Float16 f16x8 __attribute__((ext_vector_type(8)));
typedef float f32x4 __attribute__((ext_vector_type(4)));

static __device__ __forceinline__ f32x4 mfma16(f16x8 a, f16x8 b, f32x4 c) {
    return __builtin_amdgcn_mfma_f32_16x16x32_f16(a, b, c, 0, 0, 0);
}

// load 8 consecutive fp32 -> f16x8
static __device__ __forceinline__ f16x8 cvt8(const float* __restrict__ p) {
    float4 f0 = *(const float4*)(p);
    float4 f1 = *(const float4*)(p + 4);
    f16x8 h;
    h[0] = (f16)f0.x; h[1] = (f16)f0.y; h[2] = (f16)f0.z; h[3] = (f16)f0.w;
    h[4] = (f16)f1.x; h[5] = (f16)f1.y; h[6] = (f16)f1.z; h[7] = (f16)f1.w;
    return h;
}

// LDS layout (bytes). Odd-ish strides (104/72/67 elems) avoid bank conflicts.
//   q_s  @     0 : 49 x 104 f16 (10192)  Q row-major [pos][head*32+eh]
//   k_s  @ 10192 : 49 x 104 f16 (10192)  K row-major
//   vt_s @ 20384 : 96 x  72 f16 (13824)  V transposed [chan][pos]
//   o_s  @ 34208 : 64 x 104 f16 (13312)  attn out row-major [pos][chan]
//   U    @ 47520 : xs (49x104 f16) overlaid with s_s (49x67 f16, 6576B pad)
//                  + p_s (64x72 f16, 9216B)          (U = 15792)
// total 63312 (<64KB static limit, 2 blocks/CU).
// Reads may overreach a region's row count (MFMA fragment rows up to 63);
// they land in the next region -> finite/NaN garbage only in result rows >=49,
// which are never stored.
#define SMEM_BYTES 63312

__global__ __launch_bounds__(256, 2) void swin_fused(
    const float* __restrict__ x, const float* __restrict__ w1,
    const float* __restrict__ b1, const float* __restrict__ w2,
    const float* __restrict__ b2, float* __restrict__ out)
{
    __shared__ __align__(16) char smem[SMEM_BYTES];
    f16* q_s  = (f16*)(smem);
    f16* k_s  = (f16*)(smem + 10192);
    f16* vt_s = (f16*)(smem + 20384);
    f16* o_s  = (f16*)(smem + 34208);
    f16* xs   = (f16*)(smem + 47520);
    f16* s_s  = (f16*)(smem + 47520);
    f16* p_s  = (f16*)(smem + 54096);

    const int tid  = threadIdx.x;
    const int wv   = tid >> 6;        // wave id 0..3
    const int lane = tid & 63;
    const int lrow = lane & 15;
    const int lq   = lane >> 4;

    const int bx = blockIdx.x;
    const int b  = bx >> 6;
    const int wz = bx & 63;
    const int wh = wz >> 3;           // window row 0..7
    const int ww = wz & 7;            // window col 0..7

    const float* xb = x + b * (3136 * 96);

    // ---- stage x window (49 pos x 96 ch) into LDS as f16; fwd roll = -4 ----
    for (int idx = tid; idx < 49 * 24; idx += 256) {
        int p  = idx / 24, q4 = idx - p * 24;
        int i  = p / 7,    j  = p - i * 7;
        int r  = wh * 7 + i + 4; if (r >= 56) r -= 56;
        int c  = ww * 7 + j + 4; if (c >= 56) c -= 56;
        float4 v = *(const float4*)(xb + (r * 56 + c) * 96 + q4 * 4);
        f16x4 hv;
        hv[0] = (f16)v.x; hv[1] = (f16)v.y; hv[2] = (f16)v.z; hv[3] = (f16)v.w;
        *(f16x4*)(xs + p * 104 + q4 * 4) = hv;
    }
    __syncthreads();

    // ---- GEMM1: qkv[pos][n'] = x @ w1p^T + b1p,  n' = kq*96 + head*32 + eh
    //      source channel c = (head*32+eh)*3 + kq  (reshape (E,3), K fastest)
    {
        f16x8 bf[4][3];
        float bias[4];
        int   kq[4], cm[4];
        #pragma unroll
        for (int t = 0; t < 4; ++t) {
            int nt  = wv + 4 * t;             // N-tile owned by this wave
            int col = nt * 16 + lrow;         // n' in [0,256)
            int kqv = col / 96;               // 0=Q 1=K 2=V (uniform per tile)
            int r96 = col - kqv * 96;
            int srow = r96 * 3 + kqv;
            const float* wr = w1 + srow * 96;
            #pragma unroll
            for (int ks = 0; ks < 3; ++ks)
                bf[t][ks] = cvt8(wr + ks * 32 + lq * 8);
            bias[t] = b1[srow];
            kq[t] = kqv; cm[t] = r96;
        }
        #pragma unroll
        for (int mt = 0; mt < 4; ++mt) {
            f16x8 af[3];
            #pragma unroll
            for (int ks = 0; ks < 3; ++ks)
                af[ks] = *(const f16x8*)(xs + (mt * 16 + lrow) * 104 + ks * 32 + lq * 8);
            int rbase = mt * 16 + lq * 4;
            #pragma unroll
            for (int t = 0; t < 4; ++t) {
                f32x4 acc = {0.f, 0.f, 0.f, 0.f};
                #pragma unroll
                for (int ks = 0; ks < 3; ++ks) acc = mfma16(af[ks], bf[t][ks], acc);
                if (kq[t] == 0) {
                    #pragma unroll
                    for (int r2 = 0; r2 < 4; ++r2) {
                        int row = rbase + r2;
                        if (row < 49) q_s[row * 104 + cm[t]] = (f16)(acc[r2] + bias[t]);
                    }
                } else if (kq[t] == 1) {
                    #pragma unroll
                    for (int r2 = 0; r2 < 4; ++r2) {
                        int row = rbase + r2;
                        if (row < 49) k_s[row * 104 + cm[t]] = (f16)(acc[r2] + bias[t]);
                    }
                } else {
                    f16x4 pk;
                    #pragma unroll
                    for (int r2 = 0; r2 < 4; ++r2) pk[r2] = (f16)(acc[r2] + bias[t]);
                    *(f16x4*)(vt_s + cm[t] * 72 + rbase) = pk;  // transposed store
                }
            }
        }
        // tail N-tiles 16,17 (V channels 64..95) on waves 0,1
        if (wv < 2) {
            int col  = 256 + wv * 16 + lrow;
            int cmv  = col - 192;
            int srow = cmv * 3 + 2;
            const float* wr = w1 + srow * 96;
            f16x8 bt[3];
            #pragma unroll
            for (int ks = 0; ks < 3; ++ks) bt[ks] = cvt8(wr + ks * 32 + lq * 8);
            float bias = b1[srow];
            #pragma unroll
            for (int mt = 0; mt < 4; ++mt) {
                f16x8 af[3];
                #pragma unroll
                for (int ks = 0; ks < 3; ++ks)
                    af[ks] = *(const f16x8*)(xs + (mt * 16 + lrow) * 104 + ks * 32 + lq * 8);
                f32x4 acc = {0.f, 0.f, 0.f, 0.f};
                #pragma unroll
                for (int ks = 0; ks < 3; ++ks) acc = mfma16(af[ks], bt[ks], acc);
                int rbase = mt * 16 + lq * 4;
                f16x4 pk;
                #pragma unroll
                for (int r2 = 0; r2 < 4; ++r2) pk[r2] = (f16)(acc[r2] + bias);
                *(f16x4*)(vt_s + cmv * 72 + rbase) = pk;
            }
        }
    }

    const bool mrow = (wh == 7), mcol = (ww == 7);
    const float scale = 0.17677669529663687f;  // 1/sqrt(32)

    // ---- per-head attention ----
    for (int hh = 0; hh < 3; ++hh) {
        __syncthreads();
        {   // QK^T: wave = m-tile
            f16x8 aq = *(const f16x8*)(q_s + (wv * 16 + lrow) * 104 + hh * 32 + lq * 8);
            int rbase = wv * 16 + lq * 4;
            #pragma unroll
            for (int nt = 0; nt < 4; ++nt) {
                f16x8 bk = *(const f16x8*)(k_s + (nt * 16 + lrow) * 104 + hh * 32 + lq * 8);
                f32x4 z = {0.f, 0.f, 0.f, 0.f};
                f32x4 sc = mfma16(aq, bk, z);
                #pragma unroll
                for (int r2 = 0; r2 < 4; ++r2) {
                    int m = rbase + r2;
                    if (m < 49) s_s[m * 67 + nt * 16 + lrow] = (f16)sc[r2];
                }
            }
        }
        __syncthreads();
        // softmax: 4 lanes per row, 49 rows (tid<196); shift masks as predicates
        if (tid < 196) {
            int m = tid >> 2, g = tid & 3;
            int m7 = m % 7;
            bool mge = (m >= 28), mc4 = (m7 >= 4);
            auto ok = [&](int n) {
                return (!mrow || (mge == (n >= 28))) &&
                       (!mcol || (mc4 == ((n % 7) >= 4)));
            };
            float mx = -1e30f;
            for (int n = g; n < 49; n += 4)
                if (ok(n)) mx = fmaxf(mx, (float)s_s[m * 67 + n]);
            mx = fmaxf(mx, __shfl_xor(mx, 1));
            mx = fmaxf(mx, __shfl_xor(mx, 2));
            mx *= scale;
            float sum = 0.f;
            for (int n = g; n < 49; n += 4) {
                if (ok(n)) {
                    float e = __expf((float)s_s[m * 67 + n] * scale - mx);
                    s_s[m * 67 + n] = (f16)e;
                    sum += e;
                }
            }
            sum += __shfl_xor(sum, 1);
            sum += __shfl_xor(sum, 2);
            float inv = 1.f / sum;
            for (int n = g; n < 64; n += 4) {
                f16 pv = (f16)0.f;
                if (n < 49 && ok(n)) pv = (f16)((float)s_s[m * 67 + n] * inv);
                p_s[m * 72 + n] = pv;   // pad cols (incl masked) -> exact 0
            }
        }
        __syncthreads();
        {   // PV: wave = m-tile; B = vt_s rows (V^T), K-dim = pos (2 steps)
            f16x8 ap0 = *(const f16x8*)(p_s + (wv * 16 + lrow) * 72 + lq * 8);
            f16x8 ap1 = *(const f16x8*)(p_s + (wv * 16 + lrow) * 72 + 32 + lq * 8);
            int rbase = wv * 16 + lq * 4;
            #pragma unroll
            for (int et = 0; et < 2; ++et) {
                int vrow = hh * 32 + et * 16 + lrow;
                f16x8 bv0 = *(const f16x8*)(vt_s + vrow * 72 + lq * 8);
                f16x8 bv1 = *(const f16x8*)(vt_s + vrow * 72 + 32 + lq * 8);
                f32x4 z = {0.f, 0.f, 0.f, 0.f};
                f32x4 acc = mfma16(ap0, bv0, z);
                acc = mfma16(ap1, bv1, acc);
                #pragma unroll
                for (int r2 = 0; r2 < 4; ++r2)
                    o_s[(rbase + r2) * 104 + hh * 32 + et * 16 + lrow] = (f16)acc[r2];
            }
        }
    }
    __syncthreads();

    // ---- GEMM2: out = o @ w2^T + b2, scatter to +3-rolled positions ----
    {
        f16x8 ao[3];
        #pragma unroll
        for (int ks = 0; ks < 3; ++ks)
            ao[ks] = *(const f16x8*)(o_s + (wv * 16 + lrow) * 104 + ks * 32 + lq * 8);
        int rbase = wv * 16 + lq * 4;
        int opos[4];
        #pragma unroll
        for (int r2 = 0; r2 < 4; ++r2) {
            int m  = rbase + r2;
            int mm = (m < 49) ? m : 48;     // clamped; rows >=49 never stored
            int i  = mm / 7, j = mm - i * 7;
            int orow = wh * 7 + i + 3; if (orow >= 56) orow -= 56;
            int ocol = ww * 7 + j + 3; if (ocol >= 56) ocol -= 56;
            opos[r2] = (b * 3136 + orow * 56 + ocol) * 96;
        }
        #pragma unroll
        for (int nt = 0; nt < 6; ++nt) {
            int eo = nt * 16 + lrow;
            const float* wr = w2 + eo * 96;
            f32x4 acc = {0.f, 0.f, 0.f, 0.f};
            #pragma unroll
            for (int ks = 0; ks < 3; ++ks) {
                f16x8 hb = cvt8(wr + ks * 32 + lq * 8);
                acc = mfma16(ao[ks], hb, acc);
            }
            float bias = b2[eo];
            #pragma unroll
            for (int r2 = 0; r2 < 4; ++r2)
                if (rbase + r2 < 49) out[opos[r2] + eo] = acc[r2] + bias;
        }
    }
}

extern "C" void kernel_launch(void* const* d_in, const int* in_sizes, int n_in,
                              void* d_out, int out_size, void* d_ws, size_t ws_size,
                              hipStream_t stream) {
    const float* x  = (const float*)d_in[0];
    const float* w1 = (const float*)d_in[1];
    const float* b1 = (const float*)d_in[2];
    const float* w2 = (const float*)d_in[3];
    const float* b2 = (const float*)d_in[4];
    float* out = (float*)d_out;
    swin_fused<<<dim3(4096), dim3(256), 0, stream>>>(x, w1, b1, w2, b2, out);
}

// Round 4
// 284.423 us; speedup vs baseline: 1.6207x; 1.6207x over previous
//
#include <hip/hip_runtime.h>

// Fused ShiftedWindowMSA, round 4 = round 3 + NaN fix:
//  PV B-operand k=56..63 overhangs the stride-56 vt row; for vrow=95 that
//  lands in the 16B tail pad (uninitialized LDS). A-side P is 0 there, but
//  0*NaN=NaN -> zero the pad in phase 0.
// One WG per (batch, window): 4096 x 256 threads, 3 blocks/CU (52.6KB LDS).

typedef _Float16 f16;
typedef _Float16 f16x4 __attribute__((ext_vector_type(4)));
typedef _Float16 f16x8 __attribute__((ext_vector_type(8)));
typedef float f32x4 __attribute__((ext_vector_type(4)));

static __device__ __forceinline__ f32x4 mfma16(f16x8 a, f16x8 b, f32x4 c) {
    return __builtin_amdgcn_mfma_f32_16x16x32_f16(a, b, c, 0, 0, 0);
}
static __device__ __forceinline__ f16x8 cvt8(const float* __restrict__ p) {
    float4 f0 = *(const float4*)(p);
    float4 f1 = *(const float4*)(p + 4);
    f16x8 h;
    h[0]=(f16)f0.x; h[1]=(f16)f0.y; h[2]=(f16)f0.z; h[3]=(f16)f0.w;
    h[4]=(f16)f1.x; h[5]=(f16)f1.y; h[6]=(f16)f1.z; h[7]=(f16)f1.w;
    return h;
}

// LDS map (bytes):
//  xs 49x104 @0 (10192), reused as p0 (49x64) in attention
//  p1 @10192 (6272), p2 @16464 (6272)
//  q  @22736 49x104 (10192), reused as o after B3
//  k  @32928 49x104 (10192)
//  vt @43120 96x56  (10752)  V^T [chan][pos], pos 49..55 zeroed
//  +16B ZEROED pad @53872 (vrow=95 k=56..63 overhang). Total 53888.
// Garbage-safety invariants:
//  - A-row over-reads (rows>=49) only pollute D rows>=49, which are never
//    stored to global / P / out (store guards).
//  - B n-row over-reads feed softmax cols killed by the `ok` predicate
//    BEFORE exp (select, not multiply) -> NaN-safe.
//  - Every B k-overhang multiplies a guaranteed-zero A element, so the B
//    memory must be finite: vt pos 49..55 zeroed, pad zeroed, other
//    overhangs land on written V/K/Q data.
#define SMEM_BYTES 53888
#define OFF_P1 10192
#define OFF_P2 16464
#define OFF_Q  22736
#define OFF_K  32928
#define OFF_VT 43120

template<bool WS>
__global__ __launch_bounds__(256, 3) void swin_fused(
    const float* __restrict__ x, const float* __restrict__ w1,
    const float* __restrict__ b1, const float* __restrict__ w2,
    const float* __restrict__ b2, float* __restrict__ out,
    const f16* __restrict__ w1p, const f16* __restrict__ w2p,
    const float* __restrict__ b1p)
{
    __shared__ __align__(16) char smem[SMEM_BYTES];
    f16* xs   = (f16*)(smem);
    f16* q_s  = (f16*)(smem + OFF_Q);
    f16* k_s  = (f16*)(smem + OFF_K);
    f16* vt_s = (f16*)(smem + OFF_VT);
    f16* o_s  = q_s;                      // overlay after B3
    f16* p_b[3] = { (f16*)(smem), (f16*)(smem + OFF_P1), (f16*)(smem + OFF_P2) };

    const int tid  = threadIdx.x;
    const int wv   = tid >> 6;
    const int lane = tid & 63;
    const int lrow = lane & 15;
    const int lq   = lane >> 4;

    const int bx = blockIdx.x;
    const int b  = bx >> 6;
    const int wz = bx & 63;
    const int wh = wz >> 3;
    const int ww = wz & 7;

    const float* xb = x + b * (3136 * 96);

    // ---- phase 0: stage x window (fwd roll -4) + zero vt pos-pad & tail pad
    for (int idx = tid; idx < 49 * 24; idx += 256) {
        int p  = idx / 24, q4 = idx - p * 24;
        int i  = p / 7,    j  = p - i * 7;
        int r  = wh * 7 + i + 4; if (r >= 56) r -= 56;
        int c  = ww * 7 + j + 4; if (c >= 56) c -= 56;
        float4 v = *(const float4*)(xb + (r * 56 + c) * 96 + q4 * 4);
        f16x4 hv;
        hv[0]=(f16)v.x; hv[1]=(f16)v.y; hv[2]=(f16)v.z; hv[3]=(f16)v.w;
        *(f16x4*)(xs + p * 104 + q4 * 4) = hv;
    }
    if (tid < 96) {
        #pragma unroll
        for (int p7 = 49; p7 < 56; ++p7) vt_s[tid * 56 + p7] = (f16)0.f;
    }
    if (tid < 8) vt_s[96 * 56 + tid] = (f16)0.f;   // NaN fix: zero tail pad
    __syncthreads();   // B1

    // ---- phase 1: GEMM1 -> q,k (row-major), vt (transposed) ----
    {
        f16x8 bf[4][3];
        float bias[4];
        int   kq[4], cm[4];
        #pragma unroll
        for (int t = 0; t < 4; ++t) {
            int nt  = wv + 4 * t;
            int col = nt * 16 + lrow;
            int kqv = nt / 6;                 // 0..5 Q, 6..11 K, 12..15 V
            int c96 = col - kqv * 96;
            if constexpr (WS) {
                #pragma unroll
                for (int ks = 0; ks < 3; ++ks)
                    bf[t][ks] = *(const f16x8*)(w1p + col * 96 + ks * 32 + lq * 8);
                bias[t] = b1p[col];
            } else {
                int srow = c96 * 3 + kqv;
                #pragma unroll
                for (int ks = 0; ks < 3; ++ks)
                    bf[t][ks] = cvt8(w1 + srow * 96 + ks * 32 + lq * 8);
                bias[t] = b1[srow];
            }
            kq[t] = kqv; cm[t] = c96;
        }
        #pragma unroll
        for (int mt = 0; mt < 4; ++mt) {
            f16x8 af[3];
            #pragma unroll
            for (int ks = 0; ks < 3; ++ks)
                af[ks] = *(const f16x8*)(xs + (mt * 16 + lrow) * 104 + ks * 32 + lq * 8);
            int rbase = mt * 16 + lq * 4;
            #pragma unroll
            for (int t = 0; t < 4; ++t) {
                f32x4 acc = {0.f, 0.f, 0.f, 0.f};
                #pragma unroll
                for (int ks = 0; ks < 3; ++ks) acc = mfma16(af[ks], bf[t][ks], acc);
                if (kq[t] == 0) {
                    #pragma unroll
                    for (int r2 = 0; r2 < 4; ++r2) {
                        int row = rbase + r2;
                        if (row < 49) q_s[row * 104 + cm[t]] = (f16)(acc[r2] + bias[t]);
                    }
                } else if (kq[t] == 1) {
                    #pragma unroll
                    for (int r2 = 0; r2 < 4; ++r2) {
                        int row = rbase + r2;
                        if (row < 49) k_s[row * 104 + cm[t]] = (f16)(acc[r2] + bias[t]);
                    }
                } else {
                    f16x4 pk;
                    #pragma unroll
                    for (int r2 = 0; r2 < 4; ++r2) pk[r2] = (f16)(acc[r2] + bias[t]);
                    if (rbase < 45)      *(f16x4*)(vt_s + cm[t] * 56 + rbase) = pk;
                    else if (rbase == 48) vt_s[cm[t] * 56 + 48] = pk[0];
                }
            }
        }
        if (wv < 2) {   // tail N-tiles 16,17: V channels 64..95
            int col = 256 + wv * 16 + lrow;
            int c96 = col - 192;
            f16x8 bt[3];
            float biasT;
            if constexpr (WS) {
                #pragma unroll
                for (int ks = 0; ks < 3; ++ks)
                    bt[ks] = *(const f16x8*)(w1p + col * 96 + ks * 32 + lq * 8);
                biasT = b1p[col];
            } else {
                int srow = c96 * 3 + 2;
                #pragma unroll
                for (int ks = 0; ks < 3; ++ks)
                    bt[ks] = cvt8(w1 + srow * 96 + ks * 32 + lq * 8);
                biasT = b1[srow];
            }
            #pragma unroll
            for (int mt = 0; mt < 4; ++mt) {
                f16x8 af[3];
                #pragma unroll
                for (int ks = 0; ks < 3; ++ks)
                    af[ks] = *(const f16x8*)(xs + (mt * 16 + lrow) * 104 + ks * 32 + lq * 8);
                f32x4 acc = {0.f, 0.f, 0.f, 0.f};
                #pragma unroll
                for (int ks = 0; ks < 3; ++ks) acc = mfma16(af[ks], bt[ks], acc);
                int rbase = mt * 16 + lq * 4;
                f16x4 pk;
                #pragma unroll
                for (int r2 = 0; r2 < 4; ++r2) pk[r2] = (f16)(acc[r2] + biasT);
                if (rbase < 45)      *(f16x4*)(vt_s + c96 * 56 + rbase) = pk;
                else if (rbase == 48) vt_s[c96 * 56 + 48] = pk[0];
            }
        }
    }
    __syncthreads();   // B2

    const bool mrow = (wh == 7), mcol = (ww == 7);
    const float scale = 0.17677669529663687f;   // 1/sqrt(32)

    // ---- phase 2: QK^T + in-register softmax + P write; wave wv owns m-tile wv
    {
        const int mt = wv;
        const int arow = mt * 16 + lrow;
        const int mbase = mt * 16 + lq * 4;
        #pragma unroll
        for (int hh = 0; hh < 3; ++hh) {
            f16x8 aq = *(const f16x8*)(q_s + arow * 104 + hh * 32 + lq * 8);
            f32x4 sc[4];
            #pragma unroll
            for (int nt = 0; nt < 4; ++nt) {
                f16x8 bk = *(const f16x8*)(k_s + (nt * 16 + lrow) * 104 + hh * 32 + lq * 8);
                f32x4 z = {0.f, 0.f, 0.f, 0.f};
                sc[nt] = mfma16(aq, bk, z);
            }
            float ev[4][4], vmax[4], esum[4];
            #pragma unroll
            for (int r2 = 0; r2 < 4; ++r2) vmax[r2] = -3e38f;
            #pragma unroll
            for (int nt = 0; nt < 4; ++nt) {
                int  nn  = nt * 16 + lrow;
                bool nok = nn < 49;
                bool nge = nn >= 28, n4 = (nn % 7) >= 4;
                #pragma unroll
                for (int r2 = 0; r2 < 4; ++r2) {
                    int  mm = mbase + r2;
                    bool ok = nok && (!mrow || ((mm >= 28) == nge))
                                  && (!mcol || (((mm % 7) >= 4) == n4));
                    float v = ok ? sc[nt][r2] * scale : -3e38f;
                    ev[nt][r2] = v;
                    vmax[r2] = fmaxf(vmax[r2], v);
                }
            }
            #pragma unroll
            for (int r2 = 0; r2 < 4; ++r2) {
                float m0 = vmax[r2];
                m0 = fmaxf(m0, __shfl_xor(m0, 1));
                m0 = fmaxf(m0, __shfl_xor(m0, 2));
                m0 = fmaxf(m0, __shfl_xor(m0, 4));
                m0 = fmaxf(m0, __shfl_xor(m0, 8));
                vmax[r2] = m0;
                esum[r2] = 0.f;
            }
            #pragma unroll
            for (int nt = 0; nt < 4; ++nt)
                #pragma unroll
                for (int r2 = 0; r2 < 4; ++r2) {
                    float e = (ev[nt][r2] > -1e38f) ? __expf(ev[nt][r2] - vmax[r2]) : 0.f;
                    ev[nt][r2] = e;
                    esum[r2] += e;
                }
            #pragma unroll
            for (int r2 = 0; r2 < 4; ++r2) {
                float s = esum[r2];
                s += __shfl_xor(s, 1);
                s += __shfl_xor(s, 2);
                s += __shfl_xor(s, 4);
                s += __shfl_xor(s, 8);
                esum[r2] = 1.0f / s;
            }
            f16* ph = p_b[hh];
            #pragma unroll
            for (int nt = 0; nt < 4; ++nt)
                #pragma unroll
                for (int r2 = 0; r2 < 4; ++r2) {
                    int mm = mbase + r2;
                    if (mm < 49)                      // stay in 49-row buffer
                        ph[mm * 64 + nt * 16 + lrow] = (f16)(ev[nt][r2] * esum[r2]);
                }
        }
    }
    __syncthreads();   // B3

    // ---- phase 3: PV -> o (overlays q) ----
    {
        const int mt = wv;
        #pragma unroll
        for (int hh = 0; hh < 3; ++hh) {
            const f16* ph = p_b[hh];
            f16x8 ap0 = *(const f16x8*)(ph + (mt * 16 + lrow) * 64 + lq * 8);
            f16x8 ap1 = *(const f16x8*)(ph + (mt * 16 + lrow) * 64 + 32 + lq * 8);
            #pragma unroll
            for (int et = 0; et < 2; ++et) {
                int vrow = hh * 32 + et * 16 + lrow;
                f16x8 bv0 = *(const f16x8*)(vt_s + vrow * 56 + lq * 8);
                f16x8 bv1 = *(const f16x8*)(vt_s + vrow * 56 + 32 + lq * 8);
                f32x4 z = {0.f, 0.f, 0.f, 0.f};
                f32x4 acc = mfma16(ap0, bv0, z);
                acc = mfma16(ap1, bv1, acc);
                #pragma unroll
                for (int r2 = 0; r2 < 4; ++r2)
                    o_s[(mt * 16 + lq * 4 + r2) * 104 + hh * 32 + et * 16 + lrow] = (f16)acc[r2];
            }
        }
    }
    __syncthreads();   // B4

    // ---- phase 4: GEMM2 + bias, scatter to +3-rolled positions ----
    // Each wave computes ALL 6 channel tiles for its own rows.
    {
        f16x8 ao[3];
        #pragma unroll
        for (int ks = 0; ks < 3; ++ks)
            ao[ks] = *(const f16x8*)(o_s + (wv * 16 + lrow) * 104 + ks * 32 + lq * 8);
        int rbase = wv * 16 + lq * 4;
        int opos[4];
        #pragma unroll
        for (int r2 = 0; r2 < 4; ++r2) {
            int m  = rbase + r2;
            int mm = (m < 49) ? m : 48;
            int i  = mm / 7, j = mm - i * 7;
            int orow = wh * 7 + i + 3; if (orow >= 56) orow -= 56;
            int ocol = ww * 7 + j + 3; if (ocol >= 56) ocol -= 56;
            opos[r2] = (b * 3136 + orow * 56 + ocol) * 96;
        }
        #pragma unroll
        for (int nt = 0; nt < 6; ++nt) {
            int eo = nt * 16 + lrow;
            f32x4 acc = {0.f, 0.f, 0.f, 0.f};
            #pragma unroll
            for (int ks = 0; ks < 3; ++ks) {
                f16x8 hb;
                if constexpr (WS)
                    hb = *(const f16x8*)(w2p + eo * 96 + ks * 32 + lq * 8);
                else
                    hb = cvt8(w2 + eo * 96 + ks * 32 + lq * 8);
                acc = mfma16(ao[ks], hb, acc);
            }
            float bias = b2[eo];
            #pragma unroll
            for (int r2 = 0; r2 < 4; ++r2)
                if (rbase + r2 < 49) out[opos[r2] + eo] = acc[r2] + bias;
        }
    }
}

// Pre-permute + f16-convert weights into d_ws (runs every launch; graph-safe).
__global__ void prep_weights(const float* __restrict__ w1, const float* __restrict__ b1,
                             const float* __restrict__ w2,
                             f16* __restrict__ w1p, f16* __restrict__ w2p,
                             float* __restrict__ b1p)
{
    int idx = blockIdx.x * 256 + threadIdx.x;
    if (idx < 27648) {                 // w1p[n'][k], n' = kq*96 + c96
        int np = idx / 96, k = idx - np * 96;
        int kq = np / 96, c96 = np - kq * 96;
        w1p[idx] = (f16)w1[(c96 * 3 + kq) * 96 + k];
    } else if (idx < 36864) {
        int i2 = idx - 27648;
        w2p[i2] = (f16)w2[i2];
    } else if (idx < 37152) {
        int np = idx - 36864;
        int kq = np / 96, c96 = np - kq * 96;
        b1p[np] = b1[c96 * 3 + kq];
    }
}

extern "C" void kernel_launch(void* const* d_in, const int* in_sizes, int n_in,
                              void* d_out, int out_size, void* d_ws, size_t ws_size,
                              hipStream_t stream) {
    const float* x  = (const float*)d_in[0];
    const float* w1 = (const float*)d_in[1];
    const float* b1 = (const float*)d_in[2];
    const float* w2 = (const float*)d_in[3];
    const float* b2 = (const float*)d_in[4];
    float* out = (float*)d_out;

    const size_t need = 27648u * 2 + 9216u * 2 + 288u * 4;   // 74,880 B
    if (ws_size >= need) {
        f16*   w1p = (f16*)d_ws;
        f16*   w2p = w1p + 27648;
        float* b1p = (float*)(w2p + 9216);
        prep_weights<<<dim3(146), dim3(256), 0, stream>>>(w1, b1, w2, w1p, w2p, b1p);
        swin_fused<true><<<dim3(4096), dim3(256), 0, stream>>>(
            x, w1, b1, w2, b2, out, w1p, w2p, b1p);
    } else {
        swin_fused<false><<<dim3(4096), dim3(256), 0, stream>>>(
            x, w1, b1, w2, b2, out, nullptr, nullptr, nullptr);
    }
}

// Round 5
// 226.824 us; speedup vs baseline: 2.0322x; 1.2539x over previous
//
#include <hip/hip_runtime.h>

// Fused ShiftedWindowMSA, round 5: single-barrier structure.
// Key dataflow fact: after the GEMM1->attention barrier, ALL LDS dependencies
// are intra-wave (P/o/GEMM2 bands are wave-private), so no further barriers.
// GEMM1 A-fragments come straight from global x (no staging phase, no B1).
// One WG per (batch, window): 4096 x 256 threads, 4 blocks/CU (37.3KB LDS).

typedef _Float16 f16;
typedef _Float16 f16x4 __attribute__((ext_vector_type(4)));
typedef _Float16 f16x8 __attribute__((ext_vector_type(8)));
typedef float f32x4 __attribute__((ext_vector_type(4)));

static __device__ __forceinline__ f32x4 mfma16(f16x8 a, f16x8 b, f32x4 c) {
    return __builtin_amdgcn_mfma_f32_16x16x32_f16(a, b, c, 0, 0, 0);
}
static __device__ __forceinline__ f16x8 cvt8(const float* __restrict__ p) {
    float4 f0 = *(const float4*)(p);
    float4 f1 = *(const float4*)(p + 4);
    f16x8 h;
    h[0]=(f16)f0.x; h[1]=(f16)f0.y; h[2]=(f16)f0.z; h[3]=(f16)f0.w;
    h[4]=(f16)f1.x; h[5]=(f16)f1.y; h[6]=(f16)f1.z; h[7]=(f16)f1.w;
    return h;
}

// LDS map (bytes):
//  p  @0     49x72 f16 (7056)   P, rewritten per head (intra-wave round trip)
//  q  @7056  49x104 (10192)     Q row-major; overlaid by o per head/col-block
//  k  @17248 49x104 (10192)     K row-major
//  vt @27440 96x56 (10752)+16B zeroed pad   V^T [chan][pos], pos 49..55 zeroed
// total 38208 -> 4 blocks/CU.
// Garbage-safety invariants (rows 49..63 of any MFMA fragment):
//  - A-row over-reads only pollute D rows >=49, never stored (guards).
//  - Softmax kills masked/OOB cols via predicate-select BEFORE exp (NaN-safe).
//  - Every B k-overhang multiplies a guaranteed-zero A element; B memory is
//    finite there (vt pos-pad + tail pad zeroed; other overhangs land on
//    written q/k/vt data).
//  - p rows 49..63 are never written; PV A-reads of them (wave 3) produce
//    garbage only in D rows >=49 -> o-store guard drops them.
#define SMEM_BYTES 38208
#define OFF_Q  7056
#define OFF_K  17248
#define OFF_VT 27440

template<bool WS>
__global__ __launch_bounds__(256, 4) void swin_fused(
    const float* __restrict__ x, const float* __restrict__ w1,
    const float* __restrict__ b1, const float* __restrict__ w2,
    const float* __restrict__ b2, float* __restrict__ out,
    const f16* __restrict__ w1p, const f16* __restrict__ w2p,
    const float* __restrict__ b1p)
{
    __shared__ __align__(16) char smem[SMEM_BYTES];
    f16* p_s  = (f16*)(smem);
    f16* q_s  = (f16*)(smem + OFF_Q);
    f16* k_s  = (f16*)(smem + OFF_K);
    f16* vt_s = (f16*)(smem + OFF_VT);
    f16* o_s  = q_s;                      // per-head col-block overlay

    const int tid  = threadIdx.x;
    const int wv   = tid >> 6;
    const int lane = tid & 63;
    const int lrow = lane & 15;
    const int lq   = lane >> 4;

    const int bx = blockIdx.x;
    const int b  = bx >> 6;
    const int wz = bx & 63;
    const int wh = wz >> 3;
    const int ww = wz & 7;

    const float* xb = x + b * (3136 * 96);

    // ---- zero vt pos-pad (49..55) + 16B tail pad (disjoint from GEMM1 stores)
    if (tid < 96) {
        #pragma unroll
        for (int p7 = 49; p7 < 56; ++p7) vt_s[tid * 56 + p7] = (f16)0.f;
    }
    if (tid < 8) vt_s[96 * 56 + tid] = (f16)0.f;

    // ---- GEMM1: qkv = x @ w1p^T + b1p; A-fragments direct from global ----
    {
        // Preload B fragments for this wave's N-tiles (nt = wv + 4t, nt<18).
        f16x8 bf[5][3];
        float bias[5];
        int   kq[5], cm[5];
        #pragma unroll
        for (int t = 0; t < 5; ++t) {
            int nt = wv + 4 * t;
            if (nt < 18) {
                int col = nt * 16 + lrow;
                int kqv = nt / 6;             // 0..5 Q, 6..11 K, 12..17 V
                int c96 = col - kqv * 96;
                if constexpr (WS) {
                    #pragma unroll
                    for (int ks = 0; ks < 3; ++ks)
                        bf[t][ks] = *(const f16x8*)(w1p + col * 96 + ks * 32 + lq * 8);
                    bias[t] = b1p[col];
                } else {
                    int srow = c96 * 3 + kqv;
                    #pragma unroll
                    for (int ks = 0; ks < 3; ++ks)
                        bf[t][ks] = cvt8(w1 + srow * 96 + ks * 32 + lq * 8);
                    bias[t] = b1[srow];
                }
                kq[t] = kqv; cm[t] = c96;
            } else { kq[t] = -1; cm[t] = 0; bias[t] = 0.f; }
        }
        #pragma unroll
        for (int mt = 0; mt < 4; ++mt) {
            // A-fragment rows: window pos p = mt*16+lrow (clamp dup >=49)
            int p  = mt * 16 + lrow; if (p > 48) p = 48;
            int i  = p / 7, j = p - i * 7;
            int r  = wh * 7 + i + 4; if (r >= 56) r -= 56;
            int c  = ww * 7 + j + 4; if (c >= 56) c -= 56;
            const float* xr = xb + (r * 56 + c) * 96;
            f16x8 af[3];
            #pragma unroll
            for (int ks = 0; ks < 3; ++ks) af[ks] = cvt8(xr + ks * 32 + lq * 8);
            int rbase = mt * 16 + lq * 4;
            #pragma unroll
            for (int t = 0; t < 5; ++t) {
                if (kq[t] < 0) continue;
                f32x4 acc = {0.f, 0.f, 0.f, 0.f};
                #pragma unroll
                for (int ks = 0; ks < 3; ++ks) acc = mfma16(af[ks], bf[t][ks], acc);
                if (kq[t] == 0) {
                    #pragma unroll
                    for (int r2 = 0; r2 < 4; ++r2) {
                        int row = rbase + r2;
                        if (row < 49) q_s[row * 104 + cm[t]] = (f16)(acc[r2] + bias[t]);
                    }
                } else if (kq[t] == 1) {
                    #pragma unroll
                    for (int r2 = 0; r2 < 4; ++r2) {
                        int row = rbase + r2;
                        if (row < 49) k_s[row * 104 + cm[t]] = (f16)(acc[r2] + bias[t]);
                    }
                } else {
                    f16x4 pk;
                    #pragma unroll
                    for (int r2 = 0; r2 < 4; ++r2) pk[r2] = (f16)(acc[r2] + bias[t]);
                    if (rbase < 45)      *(f16x4*)(vt_s + cm[t] * 56 + rbase) = pk;
                    else if (rbase == 48) vt_s[cm[t] * 56 + 48] = pk[0];
                }
            }
        }
    }
    __syncthreads();   // THE barrier: publish q/k/vt (+pads) to all waves

    const bool mrow = (wh == 7), mcol = (ww == 7);
    const float scale = 0.17677669529663687f;   // 1/sqrt(32)
    const int mt = wv;
    const int arow  = mt * 16 + lrow;
    const int mbase = mt * 16 + lq * 4;

    // ---- per-head: QK^T -> in-reg softmax -> P -> PV -> o (no barriers) ----
    #pragma unroll
    for (int hh = 0; hh < 3; ++hh) {
        f16x8 aq = *(const f16x8*)(q_s + arow * 104 + hh * 32 + lq * 8);
        f32x4 sc[4];
        #pragma unroll
        for (int nt = 0; nt < 4; ++nt) {
            f16x8 bk = *(const f16x8*)(k_s + (nt * 16 + lrow) * 104 + hh * 32 + lq * 8);
            f32x4 z = {0.f, 0.f, 0.f, 0.f};
            sc[nt] = mfma16(aq, bk, z);
        }
        float ev[4][4], vmax[4], esum[4];
        #pragma unroll
        for (int r2 = 0; r2 < 4; ++r2) vmax[r2] = -3e38f;
        #pragma unroll
        for (int nt = 0; nt < 4; ++nt) {
            int  nn  = nt * 16 + lrow;
            bool nok = nn < 49;
            bool nge = nn >= 28, n4 = (nn % 7) >= 4;
            #pragma unroll
            for (int r2 = 0; r2 < 4; ++r2) {
                int  mm = mbase + r2;
                bool ok = nok && (!mrow || ((mm >= 28) == nge))
                              && (!mcol || (((mm % 7) >= 4) == n4));
                float v = ok ? sc[nt][r2] * scale : -3e38f;
                ev[nt][r2] = v;
                vmax[r2] = fmaxf(vmax[r2], v);
            }
        }
        #pragma unroll
        for (int r2 = 0; r2 < 4; ++r2) {
            float m0 = vmax[r2];
            m0 = fmaxf(m0, __shfl_xor(m0, 1));
            m0 = fmaxf(m0, __shfl_xor(m0, 2));
            m0 = fmaxf(m0, __shfl_xor(m0, 4));
            m0 = fmaxf(m0, __shfl_xor(m0, 8));
            vmax[r2] = m0;
            esum[r2] = 0.f;
        }
        #pragma unroll
        for (int nt = 0; nt < 4; ++nt)
            #pragma unroll
            for (int r2 = 0; r2 < 4; ++r2) {
                float e = (ev[nt][r2] > -1e38f) ? __expf(ev[nt][r2] - vmax[r2]) : 0.f;
                ev[nt][r2] = e;
                esum[r2] += e;
            }
        #pragma unroll
        for (int r2 = 0; r2 < 4; ++r2) {
            float s = esum[r2];
            s += __shfl_xor(s, 1);
            s += __shfl_xor(s, 2);
            s += __shfl_xor(s, 4);
            s += __shfl_xor(s, 8);
            esum[r2] = 1.0f / s;
        }
        #pragma unroll
        for (int nt = 0; nt < 4; ++nt)
            #pragma unroll
            for (int r2 = 0; r2 < 4; ++r2) {
                int mm = mbase + r2;
                if (mm < 49)
                    p_s[mm * 72 + nt * 16 + lrow] = (f16)(ev[nt][r2] * esum[r2]);
            }

        // PV (intra-wave P round trip; vt published at the barrier)
        f16x8 ap0 = *(const f16x8*)(p_s + arow * 72 + lq * 8);
        f16x8 ap1 = *(const f16x8*)(p_s + arow * 72 + 32 + lq * 8);
        #pragma unroll
        for (int et = 0; et < 2; ++et) {
            int vrow = hh * 32 + et * 16 + lrow;
            f16x8 bv0 = *(const f16x8*)(vt_s + vrow * 56 + lq * 8);
            f16x8 bv1 = *(const f16x8*)(vt_s + vrow * 56 + 32 + lq * 8);
            f32x4 z = {0.f, 0.f, 0.f, 0.f};
            f32x4 acc = mfma16(ap0, bv0, z);
            acc = mfma16(ap1, bv1, acc);
            #pragma unroll
            for (int r2 = 0; r2 < 4; ++r2) {
                int row = mbase + r2;
                if (row < 49)   // stay inside q/o region (k_s is still live!)
                    o_s[row * 104 + hh * 32 + et * 16 + lrow] = (f16)acc[r2];
            }
        }
    }

    // ---- GEMM2 (o band is wave-private -> no barrier) ----
    {
        f16x8 ao[3];
        #pragma unroll
        for (int ks = 0; ks < 3; ++ks)
            ao[ks] = *(const f16x8*)(o_s + arow * 104 + ks * 32 + lq * 8);
        int opos[4];
        #pragma unroll
        for (int r2 = 0; r2 < 4; ++r2) {
            int m  = mbase + r2;
            int mm = (m < 49) ? m : 48;
            int i  = mm / 7, j = mm - i * 7;
            int orow = wh * 7 + i + 3; if (orow >= 56) orow -= 56;
            int ocol = ww * 7 + j + 3; if (ocol >= 56) ocol -= 56;
            opos[r2] = (b * 3136 + orow * 56 + ocol) * 96;
        }
        #pragma unroll
        for (int nt = 0; nt < 6; ++nt) {
            int eo = nt * 16 + lrow;
            f32x4 acc = {0.f, 0.f, 0.f, 0.f};
            #pragma unroll
            for (int ks = 0; ks < 3; ++ks) {
                f16x8 hb;
                if constexpr (WS)
                    hb = *(const f16x8*)(w2p + eo * 96 + ks * 32 + lq * 8);
                else
                    hb = cvt8(w2 + eo * 96 + ks * 32 + lq * 8);
                acc = mfma16(ao[ks], hb, acc);
            }
            float bias = b2[eo];
            #pragma unroll
            for (int r2 = 0; r2 < 4; ++r2)
                if (mbase + r2 < 49) out[opos[r2] + eo] = acc[r2] + bias;
        }
    }
}

// Pre-permute + f16-convert weights into d_ws (runs every launch; graph-safe).
__global__ void prep_weights(const float* __restrict__ w1, const float* __restrict__ b1,
                             const float* __restrict__ w2,
                             f16* __restrict__ w1p, f16* __restrict__ w2p,
                             float* __restrict__ b1p)
{
    int idx = blockIdx.x * 256 + threadIdx.x;
    if (idx < 27648) {                 // w1p[n'][k], n' = kq*96 + c96
        int np = idx / 96, k = idx - np * 96;
        int kq = np / 96, c96 = np - kq * 96;
        w1p[idx] = (f16)w1[(c96 * 3 + kq) * 96 + k];
    } else if (idx < 36864) {
        int i2 = idx - 27648;
        w2p[i2] = (f16)w2[i2];
    } else if (idx < 37152) {
        int np = idx - 36864;
        int kq = np / 96, c96 = np - kq * 96;
        b1p[np] = b1[c96 * 3 + kq];
    }
}

extern "C" void kernel_launch(void* const* d_in, const int* in_sizes, int n_in,
                              void* d_out, int out_size, void* d_ws, size_t ws_size,
                              hipStream_t stream) {
    const float* x  = (const float*)d_in[0];
    const float* w1 = (const float*)d_in[1];
    const float* b1 = (const float*)d_in[2];
    const float* w2 = (const float*)d_in[3];
    const float* b2 = (const float*)d_in[4];
    float* out = (float*)d_out;

    const size_t need = 27648u * 2 + 9216u * 2 + 288u * 4;   // 74,880 B
    if (ws_size >= need) {
        f16*   w1p = (f16*)d_ws;
        f16*   w2p = w1p + 27648;
        float* b1p = (float*)(w2p + 9216);
        prep_weights<<<dim3(146), dim3(256), 0, stream>>>(w1, b1, w2, w1p, w2p, b1p);
        swin_fused<true><<<dim3(4096), dim3(256), 0, stream>>>(
            x, w1, b1, w2, b2, out, w1p, w2p, b1p);
    } else {
        swin_fused<false><<<dim3(4096), dim3(256), 0, stream>>>(
            x, w1, b1, w2, b2, out, nullptr, nullptr, nullptr);
    }
}